// Round 1
// baseline (1095.422 us; speedup 1.0000x reference)
//
#include <hip/hip_runtime.h>
#include <hip/hip_bf16.h>
#include <stdint.h>

#define DIM 512
#define HEADS 16
#define NTOK 73728
#define INNER 1344

typedef __attribute__((ext_vector_type(8))) short vbf8;
typedef __attribute__((ext_vector_type(4))) float vf4;

typedef __attribute__((address_space(1))) void as1void;
typedef __attribute__((address_space(3))) void as3void;

// ---------------- weight transpose + bf16 cast: WT[n][k] = W[k][n] ----------------
__global__ void k_transpose(const float* __restrict__ Wsrc, __hip_bfloat16* __restrict__ WT,
                            int K, int N) {
  __shared__ float tile[32][33];
  const int tx = threadIdx.x, ty = threadIdx.y;
  const int n0 = blockIdx.x * 32, k0 = blockIdx.y * 32;
#pragma unroll
  for (int i = 0; i < 32; i += 8) {
    int k = k0 + ty + i, n = n0 + tx;
    if (k < K && n < N) tile[ty + i][tx] = Wsrc[(size_t)k * N + n];
  }
  __syncthreads();
#pragma unroll
  for (int i = 0; i < 32; i += 8) {
    int n = n0 + ty + i, k = k0 + tx;
    if (n < N && k < K) WT[(size_t)n * K + k] = __float2bfloat16(tile[tx][ty + i]);
  }
}

// ---------------- LayerNorm (+ optional window partition), fp32 -> bf16 ----------------
template <bool PART>
__global__ __launch_bounds__(256) void k_ln(const float* __restrict__ x,
                                            const float* __restrict__ gw,
                                            const float* __restrict__ bw,
                                            __hip_bfloat16* __restrict__ y) {
  const int wave = threadIdx.x >> 6, lane = threadIdx.x & 63;
  const int tok = blockIdx.x * 4 + wave;
  const float* xr = x + (size_t)tok * DIM + lane * 8;
  const float4 v0 = *(const float4*)xr;
  const float4 v1 = *(const float4*)(xr + 4);
  float s = v0.x + v0.y + v0.z + v0.w + v1.x + v1.y + v1.z + v1.w;
  float ss = v0.x * v0.x + v0.y * v0.y + v0.z * v0.z + v0.w * v0.w +
             v1.x * v1.x + v1.y * v1.y + v1.z * v1.z + v1.w * v1.w;
#pragma unroll
  for (int off = 32; off > 0; off >>= 1) {
    s += __shfl_xor(s, off);
    ss += __shfl_xor(ss, off);
  }
  const float mu = s * (1.0f / DIM);
  const float rs = rsqrtf(ss * (1.0f / DIM) - mu * mu + 1e-6f);
  size_t orow;
  if (PART) {
    int b = tok / 9216, rem = tok % 9216;
    int h = rem / 96, w = rem % 96;
    orow = (size_t)(((b * 12 + (h >> 3)) * 12 + (w >> 3)) * 64 + (h & 7) * 8 + (w & 7));
  } else {
    orow = (size_t)tok;
  }
  const float4 g0 = *(const float4*)(gw + lane * 8);
  const float4 g1 = *(const float4*)(gw + lane * 8 + 4);
  const float4 b0 = *(const float4*)(bw + lane * 8);
  const float4 b1 = *(const float4*)(bw + lane * 8 + 4);
  const float vals[8] = {v0.x, v0.y, v0.z, v0.w, v1.x, v1.y, v1.z, v1.w};
  const float gg[8] = {g0.x, g0.y, g0.z, g0.w, g1.x, g1.y, g1.z, g1.w};
  const float bb[8] = {b0.x, b0.y, b0.z, b0.w, b1.x, b1.y, b1.z, b1.w};
  union {
    vbf8 v;
    __hip_bfloat16 e[8];
  } po;
#pragma unroll
  for (int j = 0; j < 8; ++j) po.e[j] = __float2bfloat16((vals[j] - mu) * rs * gg[j] + bb[j]);
  *(vbf8*)(y + orow * DIM + lane * 8) = po.v;
}

// ---------------- LDS staging via global_load_lds, source pre-swizzled (T2) ----------------
template <int ROWS>
__device__ __forceinline__ void stage_lds(const __hip_bfloat16* __restrict__ g, int ldK,
                                          char* lds, int wave, int lane) {
  constexpr int RPW = ROWS / 4;  // rows per wave
  const int r0 = wave * RPW;
  const int ro = lane >> 3;  // row within 8-row group
  const int pb = lane & 7;   // physical 16B block
  const char* src = (const char*)g + (size_t)(r0 + ro) * (size_t)(ldK * 2) + ((pb ^ ro) << 4);
  char* dst = lds + r0 * 128;
#pragma unroll
  for (int c = 0; c < RPW; c += 8) {
    __builtin_amdgcn_global_load_lds((const as1void*)(src + (size_t)c * (size_t)(ldK * 2)),
                                     (as3void*)(dst + c * 128), 16, 0, 0);
  }
}

__device__ __forceinline__ const vbf8* lds_frag(const char* base, int row, int cbbyte, int xmask) {
  return (const vbf8*)(base + row * 128 + (cbbyte ^ xmask));
}

// ---------------- 128x128 GEMM, C = A[M,K] * BT[N,K]^T, epilogue by MODE ----------------
// MODE 0: out bf16 = acc + bias           (QKV)
// MODE 1: window-reverse; outf = resid + ls*(acc+bias)  (proj)
// MODE 2: outf = resid + ls*(acc+bias)    (fc2; resid may alias outf)
template <int MODE, int NT>
__global__ __launch_bounds__(256, 2) void k_gemm128(const __hip_bfloat16* __restrict__ A,
                                                    const __hip_bfloat16* __restrict__ BT,
                                                    const float* __restrict__ bias,
                                                    void* __restrict__ outp,
                                                    const float* __restrict__ resid,
                                                    const float* __restrict__ lsv, int K, int N) {
  __shared__ alignas(16) char As[128 * 128];
  __shared__ alignas(16) char Bs[128 * 128];
  const int bid = blockIdx.x;
  const int bm = bid / NT, bn = bid % NT;
  const int tid = threadIdx.x;
  const int wave = tid >> 6, lane = tid & 63;
  const int wr = wave >> 1, wc = wave & 1;
  vf4 acc[4][4] = {};

  const __hip_bfloat16* Ab = A + (size_t)bm * 128 * K;
  const __hip_bfloat16* Bb = BT + (size_t)bn * 128 * K;
  const int arow = wr * 64 + (lane & 15);
  const int brow = wc * 64 + (lane & 15);
  const int xmask = (lane & 7) << 4;
  const int cb0 = (lane >> 4) << 4;

  for (int ko = 0; ko < K; ko += 64) {
    __syncthreads();
    stage_lds<128>(Ab + ko, K, As, wave, lane);
    stage_lds<128>(Bb + ko, K, Bs, wave, lane);
    __syncthreads();
#pragma unroll
    for (int ks = 0; ks < 2; ++ks) {
      vbf8 af[4], bfr[4];
#pragma unroll
      for (int i = 0; i < 4; ++i) {
        af[i] = *lds_frag(As, arow + i * 16, cb0 + ks * 64, xmask);
        bfr[i] = *lds_frag(Bs, brow + i * 16, cb0 + ks * 64, xmask);
      }
#pragma unroll
      for (int mi = 0; mi < 4; ++mi)
#pragma unroll
        for (int ni = 0; ni < 4; ++ni)
          acc[mi][ni] = __builtin_amdgcn_mfma_f32_16x16x32_bf16(af[mi], bfr[ni], acc[mi][ni], 0, 0, 0);
    }
  }

  const int rl = (lane >> 4) << 2;
  const int cl = lane & 15;
  const int rbase = bm * 128 + wr * 64;
  const int cbase = bn * 128 + wc * 64;
#pragma unroll
  for (int mi = 0; mi < 4; ++mi) {
#pragma unroll
    for (int j = 0; j < 4; ++j) {
      const int r = rbase + mi * 16 + rl + j;
      size_t orow;
      if (MODE == 1) {
        int m = r >> 6, t = r & 63;
        int b = m / 144, mm = m % 144;
        int wh = mm / 12, ww = mm % 12;
        int h = wh * 8 + (t >> 3), w = ww * 8 + (t & 7);
        orow = (size_t)((b * 96 + h) * 96 + w);
      } else {
        orow = (size_t)r;
      }
#pragma unroll
      for (int ni = 0; ni < 4; ++ni) {
        const int c = cbase + ni * 16 + cl;
        const float v = acc[mi][ni][j] + bias[c];
        if (MODE == 0) {
          ((__hip_bfloat16*)outp)[(size_t)r * N + c] = __float2bfloat16(v);
        } else {
          float* of = (float*)outp;
          of[orow * DIM + c] = resid[orow * DIM + c] + lsv[c] * v;
        }
      }
    }
  }
}

// ---------------- GLU GEMM: dual-half (h, gate) with fused silu ----------------
__global__ __launch_bounds__(256, 2) void k_gemm_glu(const __hip_bfloat16* __restrict__ A,
                                                     const __hip_bfloat16* __restrict__ BT,
                                                     const float* __restrict__ bias,
                                                     __hip_bfloat16* __restrict__ hout) {
  __shared__ alignas(16) char As[128 * 128];
  __shared__ alignas(16) char B0s[64 * 128];
  __shared__ alignas(16) char B1s[64 * 128];
  const int K = DIM;
  const int bid = blockIdx.x;
  const int bm = bid / 21, bn = bid % 21;
  const int tid = threadIdx.x;
  const int wave = tid >> 6, lane = tid & 63;
  const int wr = wave >> 1, wc = wave & 1;
  vf4 a0[4][2] = {}, a1[4][2] = {};

  const __hip_bfloat16* Ab = A + (size_t)bm * 128 * K;
  const __hip_bfloat16* Bb0 = BT + (size_t)(bn * 64) * K;
  const __hip_bfloat16* Bb1 = BT + (size_t)(INNER + bn * 64) * K;
  const int arow = wr * 64 + (lane & 15);
  const int brow = wc * 32 + (lane & 15);
  const int xmask = (lane & 7) << 4;
  const int cb0 = (lane >> 4) << 4;

  for (int ko = 0; ko < K; ko += 64) {
    __syncthreads();
    stage_lds<128>(Ab + ko, K, As, wave, lane);
    stage_lds<64>(Bb0 + ko, K, B0s, wave, lane);
    stage_lds<64>(Bb1 + ko, K, B1s, wave, lane);
    __syncthreads();
#pragma unroll
    for (int ks = 0; ks < 2; ++ks) {
      vbf8 af[4], b0f[2], b1f[2];
#pragma unroll
      for (int i = 0; i < 4; ++i) af[i] = *lds_frag(As, arow + i * 16, cb0 + ks * 64, xmask);
#pragma unroll
      for (int i = 0; i < 2; ++i) {
        b0f[i] = *lds_frag(B0s, brow + i * 16, cb0 + ks * 64, xmask);
        b1f[i] = *lds_frag(B1s, brow + i * 16, cb0 + ks * 64, xmask);
      }
#pragma unroll
      for (int mi = 0; mi < 4; ++mi)
#pragma unroll
        for (int ni = 0; ni < 2; ++ni) {
          a0[mi][ni] = __builtin_amdgcn_mfma_f32_16x16x32_bf16(af[mi], b0f[ni], a0[mi][ni], 0, 0, 0);
          a1[mi][ni] = __builtin_amdgcn_mfma_f32_16x16x32_bf16(af[mi], b1f[ni], a1[mi][ni], 0, 0, 0);
        }
    }
  }

  const int rl = (lane >> 4) << 2;
  const int cl = lane & 15;
  const int rbase = bm * 128 + wr * 64;
  const int cbase = bn * 64 + wc * 32;
#pragma unroll
  for (int mi = 0; mi < 4; ++mi)
#pragma unroll
    for (int j = 0; j < 4; ++j) {
      const int r = rbase + mi * 16 + rl + j;
#pragma unroll
      for (int ni = 0; ni < 2; ++ni) {
        const int c = cbase + ni * 16 + cl;
        const float a = a0[mi][ni][j] + bias[c];
        const float g = a1[mi][ni][j] + bias[INNER + c];
        const float sg = 1.0f / (1.0f + __expf(-g));
        hout[(size_t)r * INNER + c] = __float2bfloat16(a * g * sg);
      }
    }
}

// ---------------- attention: one wave per (window, head) ----------------
__global__ __launch_bounds__(64) void k_attn(const __hip_bfloat16* __restrict__ qkv,
                                             __hip_bfloat16* __restrict__ o) {
  const int blk = blockIdx.x;
  const int m = blk >> 4, hd = blk & 15;
  const int t = threadIdx.x;
  __shared__ float Kh[64][36];
  __shared__ float Vh[64][36];
  const __hip_bfloat16* base = qkv + (size_t)m * 64 * 1536 + hd * 32;
  const __hip_bfloat16* qr = base + (size_t)t * 1536;
  union UU {
    vbf8 v;
    unsigned short e[8];
  };
  float q[32];
#pragma unroll
  for (int g4 = 0; g4 < 4; ++g4) {
    UU uq, uk, uv;
    uq.v = *(const vbf8*)(qr + g4 * 8);
    uk.v = *(const vbf8*)(qr + 512 + g4 * 8);
    uv.v = *(const vbf8*)(qr + 1024 + g4 * 8);
#pragma unroll
    for (int j = 0; j < 8; ++j) {
      q[g4 * 8 + j] = __uint_as_float((unsigned)uq.e[j] << 16);
      Kh[t][g4 * 8 + j] = __uint_as_float((unsigned)uk.e[j] << 16);
      Vh[t][g4 * 8 + j] = __uint_as_float((unsigned)uv.e[j] << 16);
    }
  }
  __syncthreads();
  float s[64];
  float mx = -1e30f;
#pragma unroll
  for (int j = 0; j < 64; ++j) {
    float d = 0.0f;
#pragma unroll
    for (int dd = 0; dd < 32; ++dd) d += q[dd] * Kh[j][dd];
    d *= 0.17677669529663687f;  // 1/sqrt(32)
    s[j] = d;
    mx = fmaxf(mx, d);
  }
  float sum = 0.0f;
#pragma unroll
  for (int j = 0; j < 64; ++j) {
    const float e = __expf(s[j] - mx);
    s[j] = e;
    sum += e;
  }
  const float inv = 1.0f / sum;
  float oa[32] = {};
#pragma unroll
  for (int j = 0; j < 64; ++j) {
    const float p = s[j] * inv;
#pragma unroll
    for (int dd = 0; dd < 32; ++dd) oa[dd] += p * Vh[j][dd];
  }
  __hip_bfloat16* orow = o + (size_t)(m * 64 + t) * 512 + hd * 32;
#pragma unroll
  for (int g4 = 0; g4 < 4; ++g4) {
    union {
      vbf8 v;
      __hip_bfloat16 e[8];
    } po;
#pragma unroll
    for (int j = 0; j < 8; ++j) po.e[j] = __float2bfloat16(oa[g4 * 8 + j]);
    *(vbf8*)(orow + g4 * 8) = po.v;
  }
}

// ---------------- launch ----------------
extern "C" void kernel_launch(void* const* d_in, const int* in_sizes, int n_in, void* d_out,
                              int out_size, void* d_ws, size_t ws_size, hipStream_t stream) {
  const float* x = (const float*)d_in[0];
  const float* n1g = (const float*)d_in[1];
  const float* n1b = (const float*)d_in[2];
  const float* qkv_w = (const float*)d_in[3];
  const float* qkv_b = (const float*)d_in[4];
  const float* proj_w = (const float*)d_in[5];
  const float* proj_b = (const float*)d_in[6];
  const float* ls1 = (const float*)d_in[7];
  const float* n2g = (const float*)d_in[8];
  const float* n2b = (const float*)d_in[9];
  const float* glu_w = (const float*)d_in[10];
  const float* glu_b = (const float*)d_in[11];
  const float* fc2_w = (const float*)d_in[12];
  const float* fc2_b = (const float*)d_in[13];
  const float* ls2 = (const float*)d_in[14];

  if (ws_size < 308281344u) return;  // need ~308 MB scratch

  char* ws = (char*)d_ws;
  __hip_bfloat16* wTq = (__hip_bfloat16*)(ws + 0);          // 1536x512
  __hip_bfloat16* wTp = (__hip_bfloat16*)(ws + 1572864);    // 512x512
  __hip_bfloat16* wTg = (__hip_bfloat16*)(ws + 2097152);    // 2688x512
  __hip_bfloat16* wTf = (__hip_bfloat16*)(ws + 4849664);    // 512x1344
  __hip_bfloat16* ybuf = (__hip_bfloat16*)(ws + 6291456);   // 73728x512 (y_win -> o_win -> y2)
  __hip_bfloat16* qkvbuf = (__hip_bfloat16*)(ws + 81788928);// 73728x1536 (qkv -> h)
  float* x1 = (float*)d_out;

  dim3 tb(32, 8);
  k_transpose<<<dim3(48, 16), tb, 0, stream>>>(qkv_w, wTq, 512, 1536);
  k_transpose<<<dim3(16, 16), tb, 0, stream>>>(proj_w, wTp, 512, 512);
  k_transpose<<<dim3(84, 16), tb, 0, stream>>>(glu_w, wTg, 512, 2688);
  k_transpose<<<dim3(16, 42), tb, 0, stream>>>(fc2_w, wTf, 1344, 512);

  k_ln<true><<<18432, 256, 0, stream>>>(x, n1g, n1b, ybuf);
  k_gemm128<0, 12><<<576 * 12, 256, 0, stream>>>(ybuf, wTq, qkv_b, qkvbuf, nullptr, nullptr, 512, 1536);
  k_attn<<<18432, 64, 0, stream>>>(qkvbuf, ybuf);
  k_gemm128<1, 4><<<576 * 4, 256, 0, stream>>>(ybuf, wTp, proj_b, (void*)x1, x, ls1, 512, 512);
  k_ln<false><<<18432, 256, 0, stream>>>(x1, n2g, n2b, ybuf);
  k_gemm_glu<<<576 * 21, 256, 0, stream>>>(ybuf, wTg, glu_b, qkvbuf);
  k_gemm128<2, 4><<<576 * 4, 256, 0, stream>>>(qkvbuf, wTf, fc2_b, d_out, x1, ls2, 1344, 512);
}

// Round 2
// 810.405 us; speedup vs baseline: 1.3517x; 1.3517x over previous
//
#include <hip/hip_runtime.h>
#include <hip/hip_bf16.h>
#include <stdint.h>

#define DIM 512
#define HEADS 16
#define NTOK 73728
#define INNER 1344

typedef __attribute__((ext_vector_type(8))) short vbf8;
typedef __attribute__((ext_vector_type(4))) float vf4;

typedef __attribute__((address_space(1))) void as1void;
typedef __attribute__((address_space(3))) void as3void;

// ---------------- weight transpose + bf16 cast: WT[n][k] = W[k][n] ----------------
__global__ void k_transpose(const float* __restrict__ Wsrc, __hip_bfloat16* __restrict__ WT,
                            int K, int N) {
  __shared__ float tile[32][33];
  const int tx = threadIdx.x, ty = threadIdx.y;
  const int n0 = blockIdx.x * 32, k0 = blockIdx.y * 32;
#pragma unroll
  for (int i = 0; i < 32; i += 8) {
    int k = k0 + ty + i, n = n0 + tx;
    if (k < K && n < N) tile[ty + i][tx] = Wsrc[(size_t)k * N + n];
  }
  __syncthreads();
#pragma unroll
  for (int i = 0; i < 32; i += 8) {
    int n = n0 + ty + i, k = k0 + tx;
    if (n < N && k < K) WT[(size_t)n * K + k] = __float2bfloat16(tile[tx][ty + i]);
  }
}

// ---------------- LayerNorm (+ optional window partition), fp32 -> bf16 ----------------
template <bool PART>
__global__ __launch_bounds__(256) void k_ln(const float* __restrict__ x,
                                            const float* __restrict__ gw,
                                            const float* __restrict__ bw,
                                            __hip_bfloat16* __restrict__ y) {
  const int wave = threadIdx.x >> 6, lane = threadIdx.x & 63;
  const int tok = blockIdx.x * 4 + wave;
  const float* xr = x + (size_t)tok * DIM + lane * 8;
  const float4 v0 = *(const float4*)xr;
  const float4 v1 = *(const float4*)(xr + 4);
  float s = v0.x + v0.y + v0.z + v0.w + v1.x + v1.y + v1.z + v1.w;
  float ss = v0.x * v0.x + v0.y * v0.y + v0.z * v0.z + v0.w * v0.w +
             v1.x * v1.x + v1.y * v1.y + v1.z * v1.z + v1.w * v1.w;
#pragma unroll
  for (int off = 32; off > 0; off >>= 1) {
    s += __shfl_xor(s, off);
    ss += __shfl_xor(ss, off);
  }
  const float mu = s * (1.0f / DIM);
  const float rs = rsqrtf(ss * (1.0f / DIM) - mu * mu + 1e-6f);
  size_t orow;
  if (PART) {
    int b = tok / 9216, rem = tok % 9216;
    int h = rem / 96, w = rem % 96;
    orow = (size_t)(((b * 12 + (h >> 3)) * 12 + (w >> 3)) * 64 + (h & 7) * 8 + (w & 7));
  } else {
    orow = (size_t)tok;
  }
  const float4 g0 = *(const float4*)(gw + lane * 8);
  const float4 g1 = *(const float4*)(gw + lane * 8 + 4);
  const float4 b0 = *(const float4*)(bw + lane * 8);
  const float4 b1 = *(const float4*)(bw + lane * 8 + 4);
  const float vals[8] = {v0.x, v0.y, v0.z, v0.w, v1.x, v1.y, v1.z, v1.w};
  const float gg[8] = {g0.x, g0.y, g0.z, g0.w, g1.x, g1.y, g1.z, g1.w};
  const float bb[8] = {b0.x, b0.y, b0.z, b0.w, b1.x, b1.y, b1.z, b1.w};
  union {
    vbf8 v;
    __hip_bfloat16 e[8];
  } po;
#pragma unroll
  for (int j = 0; j < 8; ++j) po.e[j] = __float2bfloat16((vals[j] - mu) * rs * gg[j] + bb[j]);
  *(vbf8*)(y + orow * DIM + lane * 8) = po.v;
}

// ---------------- LDS staging via global_load_lds, source pre-swizzled (T2) ----------------
template <int ROWS>
__device__ __forceinline__ void stage_lds(const __hip_bfloat16* __restrict__ g, int ldK,
                                          char* lds, int wave, int lane) {
  constexpr int RPW = ROWS / 4;  // rows per wave
  const int r0 = wave * RPW;
  const int ro = lane >> 3;  // row within 8-row group
  const int pb = lane & 7;   // physical 16B block
  const char* src = (const char*)g + (size_t)(r0 + ro) * (size_t)(ldK * 2) + ((pb ^ ro) << 4);
  char* dst = lds + r0 * 128;
#pragma unroll
  for (int c = 0; c < RPW; c += 8) {
    __builtin_amdgcn_global_load_lds((const as1void*)(src + (size_t)c * (size_t)(ldK * 2)),
                                     (as3void*)(dst + c * 128), 16, 0, 0);
  }
}

__device__ __forceinline__ const vbf8* lds_frag(const char* base, int row, int cbbyte, int xmask) {
  return (const vbf8*)(base + row * 128 + (cbbyte ^ xmask));
}

// ---------------- 128x128 GEMM, C = A[M,K] * BT[N,K]^T, epilogue by MODE ----------------
template <int MODE, int NT>
__global__ __launch_bounds__(256, 2) void k_gemm128(const __hip_bfloat16* __restrict__ A,
                                                    const __hip_bfloat16* __restrict__ BT,
                                                    const float* __restrict__ bias,
                                                    void* __restrict__ outp,
                                                    const float* __restrict__ resid,
                                                    const float* __restrict__ lsv, int K, int N) {
  __shared__ alignas(16) char As[128 * 128];
  __shared__ alignas(16) char Bs[128 * 128];
  const int bid = blockIdx.x;
  const int bm = bid / NT, bn = bid % NT;
  const int tid = threadIdx.x;
  const int wave = tid >> 6, lane = tid & 63;
  const int wr = wave >> 1, wc = wave & 1;
  vf4 acc[4][4] = {};

  const __hip_bfloat16* Ab = A + (size_t)bm * 128 * K;
  const __hip_bfloat16* Bb = BT + (size_t)bn * 128 * K;
  const int arow = wr * 64 + (lane & 15);
  const int brow = wc * 64 + (lane & 15);
  const int xmask = (lane & 7) << 4;
  const int cb0 = (lane >> 4) << 4;

  for (int ko = 0; ko < K; ko += 64) {
    __syncthreads();
    stage_lds<128>(Ab + ko, K, As, wave, lane);
    stage_lds<128>(Bb + ko, K, Bs, wave, lane);
    __syncthreads();
#pragma unroll
    for (int ks = 0; ks < 2; ++ks) {
      vbf8 af[4], bfr[4];
#pragma unroll
      for (int i = 0; i < 4; ++i) {
        af[i] = *lds_frag(As, arow + i * 16, cb0 + ks * 64, xmask);
        bfr[i] = *lds_frag(Bs, brow + i * 16, cb0 + ks * 64, xmask);
      }
#pragma unroll
      for (int mi = 0; mi < 4; ++mi)
#pragma unroll
        for (int ni = 0; ni < 4; ++ni)
          acc[mi][ni] = __builtin_amdgcn_mfma_f32_16x16x32_bf16(af[mi], bfr[ni], acc[mi][ni], 0, 0, 0);
    }
  }

  const int rl = (lane >> 4) << 2;
  const int cl = lane & 15;
  const int rbase = bm * 128 + wr * 64;
  const int cbase = bn * 128 + wc * 64;
#pragma unroll
  for (int mi = 0; mi < 4; ++mi) {
#pragma unroll
    for (int j = 0; j < 4; ++j) {
      const int r = rbase + mi * 16 + rl + j;
      size_t orow;
      if (MODE == 1) {
        int m = r >> 6, t = r & 63;
        int b = m / 144, mm = m % 144;
        int wh = mm / 12, ww = mm % 12;
        int h = wh * 8 + (t >> 3), w = ww * 8 + (t & 7);
        orow = (size_t)((b * 96 + h) * 96 + w);
      } else {
        orow = (size_t)r;
      }
#pragma unroll
      for (int ni = 0; ni < 4; ++ni) {
        const int c = cbase + ni * 16 + cl;
        const float v = acc[mi][ni][j] + bias[c];
        if (MODE == 0) {
          ((__hip_bfloat16*)outp)[(size_t)r * N + c] = __float2bfloat16(v);
        } else {
          float* of = (float*)outp;
          of[orow * DIM + c] = resid[orow * DIM + c] + lsv[c] * v;
        }
      }
    }
  }
}

// ---------------- GLU GEMM: dual-half (h, gate) with fused silu ----------------
__global__ __launch_bounds__(256, 2) void k_gemm_glu(const __hip_bfloat16* __restrict__ A,
                                                     const __hip_bfloat16* __restrict__ BT,
                                                     const float* __restrict__ bias,
                                                     __hip_bfloat16* __restrict__ hout) {
  __shared__ alignas(16) char As[128 * 128];
  __shared__ alignas(16) char B0s[64 * 128];
  __shared__ alignas(16) char B1s[64 * 128];
  const int K = DIM;
  const int bid = blockIdx.x;
  const int bm = bid / 21, bn = bid % 21;
  const int tid = threadIdx.x;
  const int wave = tid >> 6, lane = tid & 63;
  const int wr = wave >> 1, wc = wave & 1;
  vf4 a0[4][2] = {}, a1[4][2] = {};

  const __hip_bfloat16* Ab = A + (size_t)bm * 128 * K;
  const __hip_bfloat16* Bb0 = BT + (size_t)(bn * 64) * K;
  const __hip_bfloat16* Bb1 = BT + (size_t)(INNER + bn * 64) * K;
  const int arow = wr * 64 + (lane & 15);
  const int brow = wc * 32 + (lane & 15);
  const int xmask = (lane & 7) << 4;
  const int cb0 = (lane >> 4) << 4;

  for (int ko = 0; ko < K; ko += 64) {
    __syncthreads();
    stage_lds<128>(Ab + ko, K, As, wave, lane);
    stage_lds<64>(Bb0 + ko, K, B0s, wave, lane);
    stage_lds<64>(Bb1 + ko, K, B1s, wave, lane);
    __syncthreads();
#pragma unroll
    for (int ks = 0; ks < 2; ++ks) {
      vbf8 af[4], b0f[2], b1f[2];
#pragma unroll
      for (int i = 0; i < 4; ++i) af[i] = *lds_frag(As, arow + i * 16, cb0 + ks * 64, xmask);
#pragma unroll
      for (int i = 0; i < 2; ++i) {
        b0f[i] = *lds_frag(B0s, brow + i * 16, cb0 + ks * 64, xmask);
        b1f[i] = *lds_frag(B1s, brow + i * 16, cb0 + ks * 64, xmask);
      }
#pragma unroll
      for (int mi = 0; mi < 4; ++mi)
#pragma unroll
        for (int ni = 0; ni < 2; ++ni) {
          a0[mi][ni] = __builtin_amdgcn_mfma_f32_16x16x32_bf16(af[mi], b0f[ni], a0[mi][ni], 0, 0, 0);
          a1[mi][ni] = __builtin_amdgcn_mfma_f32_16x16x32_bf16(af[mi], b1f[ni], a1[mi][ni], 0, 0, 0);
        }
    }
  }

  const int rl = (lane >> 4) << 2;
  const int cl = lane & 15;
  const int rbase = bm * 128 + wr * 64;
  const int cbase = bn * 64 + wc * 32;
#pragma unroll
  for (int mi = 0; mi < 4; ++mi)
#pragma unroll
    for (int j = 0; j < 4; ++j) {
      const int r = rbase + mi * 16 + rl + j;
#pragma unroll
      for (int ni = 0; ni < 2; ++ni) {
        const int c = cbase + ni * 16 + cl;
        const float a = a0[mi][ni][j] + bias[c];
        const float g = a1[mi][ni][j] + bias[INNER + c];
        const float sg = 1.0f / (1.0f + __expf(-g));
        hout[(size_t)r * INNER + c] = __float2bfloat16(a * g * sg);
      }
    }
}

// ---------------- attention: MFMA, one wave per (window, head) ----------------
// Per-wave LDS pane (bf16): P [64][72] at 0, VT [32][72] at 4608. 6912 elems/wave.
__global__ __launch_bounds__(256, 2) void k_attn_mfma(const __hip_bfloat16* __restrict__ qkv,
                                                      __hip_bfloat16* __restrict__ o) {
  __shared__ __hip_bfloat16 sm[4][6912];
  const int wave = threadIdx.x >> 6, lane = threadIdx.x & 63;
  const int task = blockIdx.x * 4 + wave;
  const int w = task >> 4, hd = task & 15;
  const int g = lane >> 4, c = lane & 15;
  __hip_bfloat16* smp = sm[wave];
  __hip_bfloat16* smv = smp + 4608;

  const __hip_bfloat16* base = qkv + (size_t)w * 64 * 1536 + hd * 32;

  // Q/K fragments straight from global (frag row = lane&15, k = g*8..g*8+7)
  vbf8 qf[4], kf[4];
#pragma unroll
  for (int i = 0; i < 4; ++i) {
    const __hip_bfloat16* qrow = base + (size_t)(i * 16 + c) * 1536 + g * 8;
    qf[i] = *(const vbf8*)qrow;
    kf[i] = *(const vbf8*)(qrow + 512);
  }

  // V: lane owns token `lane`; write transposed VT[d][t] (row stride 72)
  {
    const __hip_bfloat16* vrow = base + (size_t)lane * 1536 + 1024;
    union {
      vbf8 v;
      ushort e[8];
    } uv[4];
#pragma unroll
    for (int i = 0; i < 4; ++i) uv[i].v = *(const vbf8*)(vrow + i * 8);
#pragma unroll
    for (int d = 0; d < 32; ++d)
      ((ushort*)smv)[d * 72 + lane] = uv[d >> 3].e[d & 7];
  }

  // S = Q K^T : 16 MFMAs. C-layout: lane holds S[16iq+4g+j][16it+c], j=0..3
  vf4 st[4][4];
#pragma unroll
  for (int iq = 0; iq < 4; ++iq)
#pragma unroll
    for (int it = 0; it < 4; ++it) {
      vf4 z = {};
      st[iq][it] = __builtin_amdgcn_mfma_f32_16x16x32_bf16(qf[iq], kf[it], z, 0, 0, 0);
    }

  // softmax over rows (t-dim spans 4 tiles x 16 c-lanes); defer 1/sum to epilogue
  float inv[4][4];
#pragma unroll
  for (int iq = 0; iq < 4; ++iq) {
#pragma unroll
    for (int j = 0; j < 4; ++j) {
      float m = fmaxf(fmaxf(st[iq][0][j], st[iq][1][j]), fmaxf(st[iq][2][j], st[iq][3][j]));
      m = fmaxf(m, __shfl_xor(m, 1));
      m = fmaxf(m, __shfl_xor(m, 2));
      m = fmaxf(m, __shfl_xor(m, 4));
      m = fmaxf(m, __shfl_xor(m, 8));
      float s = 0.f;
#pragma unroll
      for (int it = 0; it < 4; ++it) {
        const float p = __expf((st[iq][it][j] - m) * 0.17677669529663687f);
        st[iq][it][j] = p;
        s += p;
      }
      s += __shfl_xor(s, 1);
      s += __shfl_xor(s, 2);
      s += __shfl_xor(s, 4);
      s += __shfl_xor(s, 8);
      inv[iq][j] = 1.0f / s;
    }
  }

  // P (bf16) row-major [64][72]
#pragma unroll
  for (int iq = 0; iq < 4; ++iq)
#pragma unroll
    for (int j = 0; j < 4; ++j) {
      const int q = iq * 16 + g * 4 + j;
#pragma unroll
      for (int it = 0; it < 4; ++it)
        smp[q * 72 + it * 16 + c] = __float2bfloat16(st[iq][it][j]);
    }

  // O = P V : A-frags from P, B-frags from VT
  vf4 ot[4][2] = {};
#pragma unroll
  for (int ks = 0; ks < 2; ++ks) {
    vbf8 pf[4], vfr[2];
#pragma unroll
    for (int iq = 0; iq < 4; ++iq)
      pf[iq] = *(const vbf8*)(smp + (iq * 16 + c) * 72 + ks * 32 + g * 8);
#pragma unroll
    for (int dt = 0; dt < 2; ++dt)
      vfr[dt] = *(const vbf8*)(smv + (dt * 16 + c) * 72 + ks * 32 + g * 8);
#pragma unroll
    for (int iq = 0; iq < 4; ++iq)
#pragma unroll
      for (int dt = 0; dt < 2; ++dt)
        ot[iq][dt] = __builtin_amdgcn_mfma_f32_16x16x32_bf16(pf[iq], vfr[dt], ot[iq][dt], 0, 0, 0);
  }

  // normalize + relayout through LDS (reuse P pane), then 16B coalesced stores
#pragma unroll
  for (int iq = 0; iq < 4; ++iq)
#pragma unroll
    for (int dt = 0; dt < 2; ++dt)
#pragma unroll
      for (int j = 0; j < 4; ++j) {
        const int q = iq * 16 + g * 4 + j;
        smp[q * 72 + dt * 16 + c] = __float2bfloat16(ot[iq][dt][j] * inv[iq][j]);
      }
  __hip_bfloat16* ob = o + (size_t)w * 64 * 512 + hd * 32;
#pragma unroll
  for (int i = 0; i < 4; ++i) {
    const int idx = i * 64 + lane;
    const int row = idx >> 2, chunk = idx & 3;
    const vbf8 val = *(const vbf8*)(smp + row * 72 + chunk * 8);
    *(vbf8*)(ob + (size_t)row * 512 + chunk * 8) = val;
  }
}

// ---------------- launch ----------------
extern "C" void kernel_launch(void* const* d_in, const int* in_sizes, int n_in, void* d_out,
                              int out_size, void* d_ws, size_t ws_size, hipStream_t stream) {
  const float* x = (const float*)d_in[0];
  const float* n1g = (const float*)d_in[1];
  const float* n1b = (const float*)d_in[2];
  const float* qkv_w = (const float*)d_in[3];
  const float* qkv_b = (const float*)d_in[4];
  const float* proj_w = (const float*)d_in[5];
  const float* proj_b = (const float*)d_in[6];
  const float* ls1 = (const float*)d_in[7];
  const float* n2g = (const float*)d_in[8];
  const float* n2b = (const float*)d_in[9];
  const float* glu_w = (const float*)d_in[10];
  const float* glu_b = (const float*)d_in[11];
  const float* fc2_w = (const float*)d_in[12];
  const float* fc2_b = (const float*)d_in[13];
  const float* ls2 = (const float*)d_in[14];

  if (ws_size < 308281344u) return;  // need ~308 MB scratch

  char* ws = (char*)d_ws;
  __hip_bfloat16* wTq = (__hip_bfloat16*)(ws + 0);           // 1536x512
  __hip_bfloat16* wTp = (__hip_bfloat16*)(ws + 1572864);     // 512x512
  __hip_bfloat16* wTg = (__hip_bfloat16*)(ws + 2097152);     // 2688x512
  __hip_bfloat16* wTf = (__hip_bfloat16*)(ws + 4849664);     // 512x1344
  __hip_bfloat16* ybuf = (__hip_bfloat16*)(ws + 6291456);    // 73728x512
  __hip_bfloat16* qkvbuf = (__hip_bfloat16*)(ws + 81788928); // 73728x1536
  float* x1 = (float*)d_out;

  dim3 tb(32, 8);
  k_transpose<<<dim3(48, 16), tb, 0, stream>>>(qkv_w, wTq, 512, 1536);
  k_transpose<<<dim3(16, 16), tb, 0, stream>>>(proj_w, wTp, 512, 512);
  k_transpose<<<dim3(84, 16), tb, 0, stream>>>(glu_w, wTg, 512, 2688);
  k_transpose<<<dim3(16, 42), tb, 0, stream>>>(fc2_w, wTf, 1344, 512);

  k_ln<true><<<18432, 256, 0, stream>>>(x, n1g, n1b, ybuf);
  k_gemm128<0, 12><<<576 * 12, 256, 0, stream>>>(ybuf, wTq, qkv_b, qkvbuf, nullptr, nullptr, 512, 1536);
  k_attn_mfma<<<4608, 256, 0, stream>>>(qkvbuf, ybuf);
  k_gemm128<1, 4><<<576 * 4, 256, 0, stream>>>(ybuf, wTp, proj_b, (void*)x1, x, ls1, 512, 512);
  k_ln<false><<<18432, 256, 0, stream>>>(x1, n2g, n2b, ybuf);
  k_gemm_glu<<<576 * 21, 256, 0, stream>>>(ybuf, wTg, glu_b, qkvbuf);
  k_gemm128<2, 4><<<576 * 4, 256, 0, stream>>>(qkvbuf, wTf, fc2_b, d_out, x1, ls2, 1344, 512);
}